// Round 15
// baseline (435.890 us; speedup 1.0000x reference)
//
#include <hip/hip_runtime.h>
#include <stdint.h>

#define T_ 8
#define N_ 4096
#define E_ 131072

typedef __attribute__((ext_vector_type(4))) float f32x4;
typedef __attribute__((ext_vector_type(8))) short s16x8;
typedef __attribute__((ext_vector_type(4))) short s16x4;

static __device__ __forceinline__ short f2bf(float f) {
    union { float f; unsigned u; } v; v.f = f;
    unsigned r = v.u + 0x7fffu + ((v.u >> 16) & 1u);   // RNE
    return (short)(r >> 16);
}
static __device__ __forceinline__ float bf2f(short s) {
    union { float f; unsigned u; } v; v.u = ((unsigned)(unsigned short)s) << 16;
    return v.f;
}

// barrier that does NOT drain vmcnt: LDS writes visible (lgkmcnt 0), global
// loads stay in flight. "memory" clobber stops reordering across it.
static __device__ __forceinline__ void bar_nodrain() {
    asm volatile("s_waitcnt lgkmcnt(0)\n\ts_barrier" ::: "memory");
}

// ---------------- xw = features @ W_lpf  (M=T*N, K=128, Nc=128), fp32 ----------------
__global__ __launch_bounds__(256) void xw_gemm(const float* __restrict__ A,
                                               const float* __restrict__ W,
                                               float* __restrict__ C) {
    __shared__ float As[32][68];    // [kk][row], padded
    __shared__ float Ws[32][132];   // [kk][col], padded
    const int m0 = blockIdx.x * 64;
    const int tid = threadIdx.x;
    const int rg = tid & 15, cg = tid >> 4;
    float acc[4][8];
#pragma unroll
    for (int r = 0; r < 4; r++)
#pragma unroll
        for (int c = 0; c < 8; c++) acc[r][c] = 0.f;

    for (int k0 = 0; k0 < 128; k0 += 32) {
#pragma unroll
        for (int s = 0; s < 2; s++) {
            int q = tid + s * 256, row = q >> 3, k4 = q & 7;
            f32x4 v = *(const f32x4*)&A[(size_t)(m0 + row) * 128 + k0 + k4 * 4];
#pragma unroll
            for (int i = 0; i < 4; i++) As[k4 * 4 + i][row] = v[i];
        }
#pragma unroll
        for (int s = 0; s < 4; s++) {
            int q = tid + s * 256, kk = q >> 5, j4 = q & 31;
            *(f32x4*)&Ws[kk][j4 * 4] = *(const f32x4*)&W[(size_t)(k0 + kk) * 128 + j4 * 4];
        }
        __syncthreads();
#pragma unroll
        for (int kk = 0; kk < 32; kk++) {
            f32x4 a  = *(const f32x4*)&As[kk][rg * 4];
            f32x4 w0 = *(const f32x4*)&Ws[kk][cg * 8];
            f32x4 w1 = *(const f32x4*)&Ws[kk][cg * 8 + 4];
#pragma unroll
            for (int r = 0; r < 4; r++)
#pragma unroll
                for (int c = 0; c < 4; c++) {
                    acc[r][c]     += a[r] * w0[c];
                    acc[r][c + 4] += a[r] * w1[c];
                }
        }
        __syncthreads();
    }
#pragma unroll
    for (int r = 0; r < 4; r++) {
        f32x4 o0 = {acc[r][0], acc[r][1], acc[r][2], acc[r][3]};
        f32x4 o1 = {acc[r][4], acc[r][5], acc[r][6], acc[r][7]};
        size_t base = (size_t)(m0 + rg * 4 + r) * 128 + cg * 8;
        *(f32x4*)&C[base] = o0;
        *(f32x4*)&C[base + 4] = o1;
    }
}

// ---------------- Yt[t][j][n] (bf16) = (j<128 ? xw : X)[t][n][j]  transposed ----------------
__global__ __launch_bounds__(256) void pack_yt(const float* __restrict__ xw,
                                               const float* __restrict__ feat,
                                               short* __restrict__ yt) {
    __shared__ float tile[32][33];
    const int t = blockIdx.z, j0 = blockIdx.y * 32, n0 = blockIdx.x * 32;
    const float* src = (j0 < 128) ? (xw + (size_t)t * N_ * 128 + j0)
                                  : (feat + (size_t)t * N_ * 128 + (j0 - 128));
    const int jj = threadIdx.x & 31, i4 = threadIdx.x >> 5;
#pragma unroll
    for (int s = 0; s < 4; s++) {
        int ii = i4 * 4 + s;
        tile[ii][jj] = src[(size_t)(n0 + ii) * 128 + jj];
    }
    __syncthreads();
    const int nn = threadIdx.x & 31, j4 = threadIdx.x >> 5;
#pragma unroll
    for (int s = 0; s < 4; s++) {
        int j2 = j4 * 4 + s;
        yt[(size_t)(t * 256 + j0 + j2) * N_ + n0 + nn] = f2bf(tile[nn][j2]);
    }
}

// ---------------- Z[t] = P[t] @ Y[t]   (bf16 MFMA, fp32 acc; P converted in-kernel) ----------------
// BM=128, BK=64, double-buffered LDS + 2 named reg sets + RAW barriers
// (lgkm-only, no vmcnt(0) drain): loads stay in flight across barriers,
// dep-based counted vmcnt at each LDS store. Validated round 14 (bit-identical).
__global__ __launch_bounds__(512) void pfy_gemm(const float* __restrict__ P,
                                                const short* __restrict__ Yt,
                                                float* __restrict__ Z) {
    __shared__ short As[2][128][72];   // [buf][row][k], 144B stride
    __shared__ short Bs[2][256][72];   // [buf][col][k]
    const int t = blockIdx.y;
    const int m0 = blockIdx.x * 128;
    const int tid = threadIdx.x;
    const int lane = tid & 63, wid = tid >> 6;
    const int wm = wid >> 2, wn = wid & 3;       // wave grid 2(M) x 4(N)
    const int frow = lane & 15, kq = lane >> 4;  // MFMA fragment coords

    const float* Pt = P + (size_t)t * N_ * N_;
    const short* Bt = Yt + (size_t)t * 256 * N_;

    const int ar = tid >> 2;           // A row 0..127
    const int ak16 = (tid & 3) * 16;   // k offset (floats)
    const int bj = tid >> 1;           // B row 0..255
    const int bk32 = (tid & 1) * 32;   // k offset (shorts)

    f32x4 acc[4][4];
    f32x4 zf = {0.f, 0.f, 0.f, 0.f};
#pragma unroll
    for (int m = 0; m < 4; m++)
#pragma unroll
        for (int n = 0; n < 4; n++) acc[m][n] = zf;

    // two named register sets: even tiles -> set A, odd tiles -> set B
    f32x4 aA[4], aB[4]; s16x8 bA[4], bB[4];

    const float* Pr = &Pt[(size_t)(m0 + ar) * 4096 + ak16];
    const short* Br = &Bt[(size_t)bj * 4096 + bk32];

#define LOADA(KT) do { const int k0_ = (KT) * 64;                              \
        _Pragma("unroll") for (int i = 0; i < 4; i++)                          \
            aA[i] = *(const f32x4*)&Pr[k0_ + i * 4];                           \
        _Pragma("unroll") for (int i = 0; i < 4; i++)                          \
            bA[i] = *(const s16x8*)&Br[k0_ + i * 8]; } while (0)
#define LOADB(KT) do { const int k0_ = (KT) * 64;                              \
        _Pragma("unroll") for (int i = 0; i < 4; i++)                          \
            aB[i] = *(const f32x4*)&Pr[k0_ + i * 4];                           \
        _Pragma("unroll") for (int i = 0; i < 4; i++)                          \
            bB[i] = *(const s16x8*)&Br[k0_ + i * 8]; } while (0)
#define STOREA(BUF) do {                                                       \
        _Pragma("unroll") for (int i = 0; i < 4; i++) {                        \
            s16x4 c4_;                                                         \
            _Pragma("unroll") for (int j = 0; j < 4; j++) c4_[j] = f2bf(aA[i][j]); \
            *(s16x4*)&As[BUF][ar][ak16 + i * 4] = c4_; }                       \
        _Pragma("unroll") for (int i = 0; i < 4; i++)                          \
            *(s16x8*)&Bs[BUF][bj][bk32 + i * 8] = bA[i]; } while (0)
#define STOREB(BUF) do {                                                       \
        _Pragma("unroll") for (int i = 0; i < 4; i++) {                        \
            s16x4 c4_;                                                         \
            _Pragma("unroll") for (int j = 0; j < 4; j++) c4_[j] = f2bf(aB[i][j]); \
            *(s16x4*)&As[BUF][ar][ak16 + i * 4] = c4_; }                       \
        _Pragma("unroll") for (int i = 0; i < 4; i++)                          \
            *(s16x8*)&Bs[BUF][bj][bk32 + i * 8] = bB[i]; } while (0)

    auto compute_t = [&](int buf) {
#pragma unroll
        for (int ks = 0; ks < 2; ks++) {
            s16x8 af[4], bfr[4];
#pragma unroll
            for (int m = 0; m < 4; m++)
                af[m] = *(const s16x8*)&As[buf][wm * 64 + m * 16 + frow][kq * 8 + ks * 32];
#pragma unroll
            for (int n = 0; n < 4; n++)
                bfr[n] = *(const s16x8*)&Bs[buf][wn * 64 + n * 16 + frow][kq * 8 + ks * 32];
#pragma unroll
            for (int m = 0; m < 4; m++)
#pragma unroll
                for (int n = 0; n < 4; n++)
                    acc[m][n] = __builtin_amdgcn_mfma_f32_16x16x32_bf16(af[m], bfr[n], acc[m][n], 0, 0, 0);
        }
    };

    // prologue: tile0 -> buf0; tiles 1,2 in flight across the barrier
    LOADA(0);
    STOREA(0);            // dep-based counted vmcnt on tile0's loads only
    LOADB(1);
    LOADA(2);
    bar_nodrain();        // buf0 visible; 16 loads still outstanding

#pragma unroll 2
    for (int kt = 0; kt < 64; kt++) {
        compute_t(kt & 1);
        if (kt < 63) {
            if ((kt & 1) == 0) {
                STOREB(1);                     // tile kt+1 (odd) -> buf1
                if (kt + 3 < 64) LOADB(kt + 3);
            } else {
                STOREA(0);                     // tile kt+1 (even) -> buf0
                if (kt + 3 < 64) LOADA(kt + 3);
            }
            bar_nodrain();
        }
    }
#undef LOADA
#undef LOADB
#undef STOREA
#undef STOREB

    float* Zt = Z + (size_t)t * N_ * 256;
#pragma unroll
    for (int m = 0; m < 4; m++)
#pragma unroll
        for (int n = 0; n < 4; n++)
#pragma unroll
            for (int r = 0; r < 4; r++) {
                int row = m0 + wm * 64 + m * 16 + kq * 4 + r;  // C/D: row=(lane>>4)*4+reg
                int col = wn * 64 + n * 16 + frow;             //      col=lane&15
                Zt[(size_t)row * 256 + col] = acc[m][n][r];
            }
}

// ---------------- high = relu((X-PX)@W_hpf+b) -> xseq[:,128:] (bf16 hi/lo); low -> [:,:128] ----------------
__global__ __launch_bounds__(256) void hp_gemm(const float* __restrict__ feat,
                                               const float* __restrict__ Z,
                                               const float* __restrict__ W,
                                               const float* __restrict__ b_hpf,
                                               const float* __restrict__ b_lpf,
                                               short* __restrict__ xhi,
                                               short* __restrict__ xlo) {
    __shared__ float As[32][68];
    __shared__ float Ws[32][132];
    const int m0 = blockIdx.x * 64;
    const int tid = threadIdx.x;
    const int rg = tid & 15, cg = tid >> 4;
    float acc[4][8];
#pragma unroll
    for (int r = 0; r < 4; r++)
#pragma unroll
        for (int c = 0; c < 8; c++) acc[r][c] = 0.f;

    for (int k0 = 0; k0 < 128; k0 += 32) {
#pragma unroll
        for (int s = 0; s < 2; s++) {
            int q = tid + s * 256, row = q >> 3, k4 = q & 7;
            f32x4 fv = *(const f32x4*)&feat[(size_t)(m0 + row) * 128 + k0 + k4 * 4];
            f32x4 zv = *(const f32x4*)&Z[(size_t)(m0 + row) * 256 + 128 + k0 + k4 * 4];
#pragma unroll
            for (int i = 0; i < 4; i++) As[k4 * 4 + i][row] = fv[i] - zv[i];
        }
#pragma unroll
        for (int s = 0; s < 4; s++) {
            int q = tid + s * 256, kk = q >> 5, j4 = q & 31;
            *(f32x4*)&Ws[kk][j4 * 4] = *(const f32x4*)&W[(size_t)(k0 + kk) * 128 + j4 * 4];
        }
        __syncthreads();
#pragma unroll
        for (int kk = 0; kk < 32; kk++) {
            f32x4 a  = *(const f32x4*)&As[kk][rg * 4];
            f32x4 w0 = *(const f32x4*)&Ws[kk][cg * 8];
            f32x4 w1 = *(const f32x4*)&Ws[kk][cg * 8 + 4];
#pragma unroll
            for (int r = 0; r < 4; r++)
#pragma unroll
                for (int c = 0; c < 4; c++) {
                    acc[r][c]     += a[r] * w0[c];
                    acc[r][c + 4] += a[r] * w1[c];
                }
        }
        __syncthreads();
    }
    float bh[8];
#pragma unroll
    for (int c = 0; c < 8; c++) bh[c] = b_hpf[cg * 8 + c];
#pragma unroll
    for (int r = 0; r < 4; r++) {
        s16x4 h0, h1, l0, l1;
#pragma unroll
        for (int c = 0; c < 4; c++) {
            float v0 = fmaxf(acc[r][c] + bh[c], 0.f);
            float v1 = fmaxf(acc[r][c + 4] + bh[c + 4], 0.f);
            h0[c] = f2bf(v0); l0[c] = f2bf(v0 - bf2f(h0[c]));
            h1[c] = f2bf(v1); l1[c] = f2bf(v1 - bf2f(h1[c]));
        }
        size_t base = (size_t)(m0 + rg * 4 + r) * 256 + 128 + cg * 8;
        *(s16x4*)&xhi[base] = h0;  *(s16x4*)&xhi[base + 4] = h1;
        *(s16x4*)&xlo[base] = l0;  *(s16x4*)&xlo[base + 4] = l1;
    }
    // low half: relu(Z[:, :128] + b_lpf)
#pragma unroll
    for (int s = 0; s < 8; s++) {
        int q = tid + s * 256, row = q >> 5, j4 = q & 31;
        f32x4 z = *(const f32x4*)&Z[(size_t)(m0 + row) * 256 + j4 * 4];
        f32x4 bb = *(const f32x4*)&b_lpf[j4 * 4];
        s16x4 hi, lo;
#pragma unroll
        for (int i = 0; i < 4; i++) {
            float v = fmaxf(z[i] + bb[i], 0.f);
            hi[i] = f2bf(v); lo[i] = f2bf(v - bf2f(hi[i]));
        }
        size_t base = (size_t)(m0 + row) * 256 + j4 * 4;
        *(s16x4*)&xhi[base] = hi;
        *(s16x4*)&xlo[base] = lo;
    }
}

// ---------------- Wc gate-interleaved: packed row j <-> orig row (j&3)*256 + (j>>2) ----------------
__global__ __launch_bounds__(256) void pack_wc(const float* __restrict__ W_ih,
                                               const float* __restrict__ W_hh,
                                               short* __restrict__ whi,
                                               short* __restrict__ wlo) {
    int idx = (blockIdx.x * 256 + threadIdx.x) * 4;   // over 1024*512
    int j = idx >> 9, k = idx & 511;
    int orig = (j & 3) * 256 + (j >> 2);
    const float* src = (k < 256) ? &W_ih[(size_t)orig * 256 + k]
                                 : &W_hh[(size_t)orig * 256 + (k - 256)];
    f32x4 v = *(const f32x4*)src;
    s16x4 hi, lo;
#pragma unroll
    for (int i = 0; i < 4; i++) {
        hi[i] = f2bf(v[i]);
        lo[i] = f2bf(v[i] - bf2f(hi[i]));
    }
    *(s16x4*)&whi[idx] = hi;
    *(s16x4*)&wlo[idx] = lo;
}

// ---------------- bsum[j] = b_ih[orig(j)] + b_hh[orig(j)], gate-interleaved ----------------
__global__ void pack_bias(const float* __restrict__ b_ih,
                          const float* __restrict__ b_hh,
                          float* __restrict__ bsum) {
    int j = blockIdx.x * 256 + threadIdx.x;
    int orig = (j & 3) * 256 + (j >> 2);
    bsum[j] = b_ih[orig] + b_hh[orig];
}

// ---------------- fused LSTM step: gates GEMM + pointwise c/h ----------------
// K-loop barriers are lgkm-only (no vmcnt drain): the 4 prefetch loads issued
// at iteration top stay in flight across both barriers; dep-based counted
// vmcnt at store_t. Same validated pattern as pfy_gemm.
__global__ __launch_bounds__(512) void lstm_step(const short* __restrict__ xhi,
                                                 const short* __restrict__ xlo,
                                                 const short* __restrict__ hhi_r,
                                                 const short* __restrict__ hlo_r,
                                                 const short* __restrict__ wchi,
                                                 const short* __restrict__ wclo,
                                                 const float* __restrict__ bsum,
                                                 float* __restrict__ cbuf,
                                                 short* __restrict__ hhi_w,
                                                 short* __restrict__ hlo_w) {
    __shared__ short Ah[2][128][40], Al[2][128][40];
    __shared__ short Bh[2][128][40], Bl[2][128][40];
    __shared__ float gl[128][132];     // 16B-aligned row stride (528 B)
    const int m0 = blockIdx.x * 128;
    const int j0 = blockIdx.y * 128;
    const int tid = threadIdx.x;
    const int lane = tid & 63, wid = tid >> 6;
    const int wm = wid >> 2, wn = wid & 3;
    const int frow = lane & 15, kq = lane >> 4;

    const int sr = tid >> 2;
    const int sk8 = (tid & 3) * 8;

    f32x4 acc[4][2];
    f32x4 zf = {0.f, 0.f, 0.f, 0.f};
#pragma unroll
    for (int m = 0; m < 4; m++)
#pragma unroll
        for (int n = 0; n < 2; n++) acc[m][n] = zf;

    s16x8 a_h, a_l, b_h, b_l;

    auto load_t = [&](int kt) {
        const int k0 = kt * 32;
        const short* ah = (k0 < 256) ? xhi : hhi_r;
        const short* al = (k0 < 256) ? xlo : hlo_r;
        const size_t abase = (size_t)(m0 + sr) * 256 + (k0 & 255) + sk8;
        a_h = *(const s16x8*)&ah[abase];
        a_l = *(const s16x8*)&al[abase];
        const size_t bb = (size_t)(j0 + sr) * 512 + k0 + sk8;
        b_h = *(const s16x8*)&wchi[bb];
        b_l = *(const s16x8*)&wclo[bb];
    };
    auto store_t = [&](int buf) {
        *(s16x8*)&Ah[buf][sr][sk8] = a_h;
        *(s16x8*)&Al[buf][sr][sk8] = a_l;
        *(s16x8*)&Bh[buf][sr][sk8] = b_h;
        *(s16x8*)&Bl[buf][sr][sk8] = b_l;
    };
    auto compute_t = [&](int buf) {
        s16x8 afh[4], afl[4], bfh[2], bfl[2];
#pragma unroll
        for (int m = 0; m < 4; m++) {
            afh[m] = *(const s16x8*)&Ah[buf][wm * 64 + m * 16 + frow][kq * 8];
            afl[m] = *(const s16x8*)&Al[buf][wm * 64 + m * 16 + frow][kq * 8];
        }
#pragma unroll
        for (int n = 0; n < 2; n++) {
            bfh[n] = *(const s16x8*)&Bh[buf][wn * 32 + n * 16 + frow][kq * 8];
            bfl[n] = *(const s16x8*)&Bl[buf][wn * 32 + n * 16 + frow][kq * 8];
        }
#pragma unroll
        for (int m = 0; m < 4; m++)
#pragma unroll
            for (int n = 0; n < 2; n++) {
                acc[m][n] = __builtin_amdgcn_mfma_f32_16x16x32_bf16(afh[m], bfh[n], acc[m][n], 0, 0, 0);
                acc[m][n] = __builtin_amdgcn_mfma_f32_16x16x32_bf16(afh[m], bfl[n], acc[m][n], 0, 0, 0);
                acc[m][n] = __builtin_amdgcn_mfma_f32_16x16x32_bf16(afl[m], bfh[n], acc[m][n], 0, 0, 0);
            }
    };

    load_t(0);
    store_t(0);
    bar_nodrain();
#pragma unroll 2
    for (int kt = 0; kt < 16; kt++) {
        const int cur = kt & 1;
        if (kt < 15) load_t(kt + 1);
        compute_t(cur);
        bar_nodrain();                 // all waves done reading buf cur (lgkm)
        if (kt < 15) { store_t(cur ^ 1); bar_nodrain(); }
    }

    // epilogue: acc -> gl tile (distinct LDS array)
#pragma unroll
    for (int m = 0; m < 4; m++)
#pragma unroll
        for (int n = 0; n < 2; n++)
#pragma unroll
            for (int r = 0; r < 4; r++)
                gl[wm * 64 + m * 16 + kq * 4 + r][wn * 32 + n * 16 + frow] = acc[m][n][r];
    bar_nodrain();

    // pointwise: thread -> (row, 8 channels); gates i,f,g,o adjacent in packed cols
    const int erow = tid >> 2;
    const int ec0 = (tid & 3) * 8;
    const size_t cbase = (size_t)(m0 + erow) * 256 + blockIdx.y * 32 + ec0;
    f32x4 co0 = *(const f32x4*)&cbuf[cbase];
    f32x4 co1 = *(const f32x4*)&cbuf[cbase + 4];
    f32x4 cn0, cn1;
    s16x8 h8, l8;
#pragma unroll
    for (int i = 0; i < 8; i++) {
        f32x4 g4 = *(const f32x4*)&gl[erow][(ec0 + i) * 4];
        f32x4 bs = *(const f32x4*)&bsum[j0 + (ec0 + i) * 4];
        float si = 1.f / (1.f + expf(-(g4[0] + bs[0])));
        float sf = 1.f / (1.f + expf(-(g4[1] + bs[1])));
        float tg = tanhf(g4[2] + bs[2]);
        float so = 1.f / (1.f + expf(-(g4[3] + bs[3])));
        float cold = (i < 4) ? co0[i] : co1[i - 4];
        float cn = sf * cold + si * tg;
        float hv = so * tanhf(cn);
        if (i < 4) cn0[i] = cn; else cn1[i - 4] = cn;
        h8[i] = f2bf(hv);
        l8[i] = f2bf(hv - bf2f(h8[i]));
    }
    *(f32x4*)&cbuf[cbase] = cn0;
    *(f32x4*)&cbuf[cbase + 4] = cn1;
    *(s16x8*)&hhi_w[cbase] = h8;
    *(s16x8*)&hlo_w[cbase] = l8;
}

// ---------------- W1 [512][256] -> combined per-node weight Bc[j][k] hi/lo ----------------
__global__ __launch_bounds__(256) void pack_w1c(const float* __restrict__ W1,
                                                short* __restrict__ whi,
                                                short* __restrict__ wlo) {
    __shared__ float tile[32][33];
    const int k0 = blockIdx.x * 32;
    const int j0 = blockIdx.y * 32;
    const int koff = (j0 >= 256) ? 256 : 0;
    const int joff = (j0 >= 256) ? 256 : 0;
    const int jj = threadIdx.x & 31, k4 = threadIdx.x >> 5;
#pragma unroll
    for (int s = 0; s < 4; s++) {
        int kk = k4 * 4 + s;
        tile[kk][jj] = W1[(size_t)(k0 + kk + koff) * 256 + (j0 + jj - joff)];
    }
    __syncthreads();
    const int kk2 = threadIdx.x & 31, j4 = threadIdx.x >> 5;
#pragma unroll
    for (int s = 0; s < 4; s++) {
        int j2 = j4 * 4 + s;
        float v = tile[kk2][j2];
        short hb = f2bf(v);
        whi[(size_t)(j0 + j2) * 256 + k0 + kk2] = hb;
        wlo[(size_t)(j0 + j2) * 256 + k0 + kk2] = f2bf(v - bf2f(hb));
    }
}

// ---------------- UV = h @ Bc^T  (M=4096, K=256, N=512) ----------------
__global__ __launch_bounds__(512) void uv_gemm(const short* __restrict__ hhi,
                                               const short* __restrict__ hlo,
                                               const short* __restrict__ whi,
                                               const short* __restrict__ wlo,
                                               float* __restrict__ UV) {
    __shared__ short Ah[2][128][40], Al[2][128][40];
    __shared__ short Bh[2][128][40], Bl[2][128][40];
    const int m0 = blockIdx.x * 128;
    const int j0 = blockIdx.y * 128;
    const int tid = threadIdx.x;
    const int lane = tid & 63, wid = tid >> 6;
    const int wm = wid >> 2, wn = wid & 3;
    const int frow = lane & 15, kq = lane >> 4;
    const int sr = tid >> 2;
    const int sk8 = (tid & 3) * 8;

    f32x4 acc[4][2];
    f32x4 zf = {0.f, 0.f, 0.f, 0.f};
#pragma unroll
    for (int m = 0; m < 4; m++)
#pragma unroll
        for (int n = 0; n < 2; n++) acc[m][n] = zf;

    s16x8 a_h, a_l, b_h, b_l;

    auto load_t = [&](int kt) {
        const int k0 = kt * 32;
        const size_t abase = (size_t)(m0 + sr) * 256 + k0 + sk8;
        a_h = *(const s16x8*)&hhi[abase];
        a_l = *(const s16x8*)&hlo[abase];
        const size_t bb = (size_t)(j0 + sr) * 256 + k0 + sk8;
        b_h = *(const s16x8*)&whi[bb];
        b_l = *(const s16x8*)&wlo[bb];
    };
    auto store_t = [&](int buf) {
        *(s16x8*)&Ah[buf][sr][sk8] = a_h;
        *(s16x8*)&Al[buf][sr][sk8] = a_l;
        *(s16x8*)&Bh[buf][sr][sk8] = b_h;
        *(s16x8*)&Bl[buf][sr][sk8] = b_l;
    };
    auto compute_t = [&](int buf) {
        s16x8 afh[4], afl[4], bfh[2], bfl[2];
#pragma unroll
        for (int m = 0; m < 4; m++) {
            afh[m] = *(const s16x8*)&Ah[buf][wm * 64 + m * 16 + frow][kq * 8];
            afl[m] = *(const s16x8*)&Al[buf][wm * 64 + m * 16 + frow][kq * 8];
        }
#pragma unroll
        for (int n = 0; n < 2; n++) {
            bfh[n] = *(const s16x8*)&Bh[buf][wn * 32 + n * 16 + frow][kq * 8];
            bfl[n] = *(const s16x8*)&Bl[buf][wn * 32 + n * 16 + frow][kq * 8];
        }
#pragma unroll
        for (int m = 0; m < 4; m++)
#pragma unroll
            for (int n = 0; n < 2; n++) {
                acc[m][n] = __builtin_amdgcn_mfma_f32_16x16x32_bf16(afh[m], bfh[n], acc[m][n], 0, 0, 0);
                acc[m][n] = __builtin_amdgcn_mfma_f32_16x16x32_bf16(afh[m], bfl[n], acc[m][n], 0, 0, 0);
                acc[m][n] = __builtin_amdgcn_mfma_f32_16x16x32_bf16(afl[m], bfh[n], acc[m][n], 0, 0, 0);
            }
    };

    load_t(0);
    store_t(0);
    bar_nodrain();
#pragma unroll 2
    for (int kt = 0; kt < 8; kt++) {
        const int cur = kt & 1;
        if (kt < 7) load_t(kt + 1);
        compute_t(cur);
        bar_nodrain();
        if (kt < 7) { store_t(cur ^ 1); bar_nodrain(); }
    }

#pragma unroll
    for (int m = 0; m < 4; m++)
#pragma unroll
        for (int n = 0; n < 2; n++)
#pragma unroll
            for (int r = 0; r < 4; r++) {
                int row = m0 + wm * 64 + m * 16 + kq * 4 + r;
                int col = j0 + wn * 32 + n * 16 + frow;
                UV[(size_t)row * 512 + col] = acc[m][n][r];
            }
}

// ---------------- per-edge: logit = relu(U[src]+V[dst]+b1) . W2 + b2 ----------------
__global__ __launch_bounds__(256) void mlp_edge(const float* __restrict__ UV,
                                                const int* __restrict__ eidx,
                                                const float* __restrict__ b1,
                                                const float* __restrict__ W2,
                                                const float* __restrict__ b2,
                                                float* __restrict__ out) {
    const int e = blockIdx.x * 4 + (threadIdx.x >> 6);
    const int lane = threadIdx.x & 63;
    const int c4 = lane * 4;
    const int src = eidx[e];
    const int dst = eidx[E_ + e];
    f32x4 u = *(const f32x4*)&UV[(size_t)src * 512 + c4];
    f32x4 v = *(const f32x4*)&UV[(size_t)dst * 512 + 256 + c4];
    f32x4 bb = *(const f32x4*)&b1[c4];
    f32x4 ww = *(const f32x4*)&W2[c4];
    float p = 0.f;
#pragma unroll
    for (int i = 0; i < 4; i++)
        p += fmaxf(u[i] + v[i] + bb[i], 0.f) * ww[i];
    p += __shfl_xor(p, 1);
    p += __shfl_xor(p, 2);
    p += __shfl_xor(p, 4);
    p += __shfl_xor(p, 8);
    p += __shfl_xor(p, 16);
    p += __shfl_xor(p, 32);
    if (lane == 0) out[e] = p + b2[0];
}

extern "C" void kernel_launch(void* const* d_in, const int* in_sizes, int n_in,
                              void* d_out, int out_size, void* d_ws, size_t ws_size,
                              hipStream_t stream) {
    (void)in_sizes; (void)n_in; (void)out_size; (void)ws_size;
    const float* feat  = (const float*)d_in[0];
    const float* P     = (const float*)d_in[1];
    const int*   eidx  = (const int*)d_in[2];
    const float* W_lpf = (const float*)d_in[3];
    const float* b_lpf = (const float*)d_in[4];
    const float* W_hpf = (const float*)d_in[5];
    const float* b_hpf = (const float*)d_in[6];
    const float* W_ih  = (const float*)d_in[7];
    const float* W_hh  = (const float*)d_in[8];
    const float* b_ih  = (const float*)d_in[9];
    const float* b_hh  = (const float*)d_in[10];
    const float* W1    = (const float*)d_in[11];
    const float* b1    = (const float*)d_in[12];
    const float* W2    = (const float*)d_in[13];
    const float* b2    = (const float*)d_in[14];
    float* out = (float*)d_out;

    // workspace layout (100.7 MB)
    char* ws = (char*)d_ws;
    float* xw    = (float*)ws;   ws += (size_t)T_ * N_ * 128 * 4;   // 16.78 MB
    char*  ytreg = ws;           ws += (size_t)T_ * 256 * N_ * 2;   // 16.78 MB; later c + h dbuf
    char*  Zreg  = ws;           ws += (size_t)T_ * N_ * 256 * 4;   // 33.55 MB; later packs+UV
    short* xhi   = (short*)ws;   ws += (size_t)T_ * N_ * 256 * 2;   // 16.78 MB
    short* xlo   = (short*)ws;   ws += (size_t)T_ * N_ * 256 * 2;   // 16.78 MB

    short* yt    = (short*)ytreg;
    float* Z     = (float*)Zreg;
    // ytreg after pfy: c (4 MB) + double-buffered h hi/lo (4 x 2 MB)
    float* cbuf  = (float*)ytreg;
    short* hhi0  = (short*)(ytreg + (size_t)N_ * 256 * 4);
    short* hlo0  = hhi0 + (size_t)N_ * 256;
    short* hhi1  = hlo0 + (size_t)N_ * 256;
    short* hlo1  = hhi1 + (size_t)N_ * 256;
    // Zreg after hp_gemm: W packs + bias + UV
    short* w1chi = (short*)Zreg;
    short* w1clo = w1chi + (size_t)512 * 256;
    short* wchi  = w1clo + (size_t)512 * 256;
    short* wclo  = wchi + (size_t)1024 * 512;
    float* bsum  = (float*)(wclo + (size_t)1024 * 512);
    float* UV    = bsum + 1024;

    xw_gemm<<<dim3(T_ * N_ / 64), 256, 0, stream>>>(feat, W_lpf, xw);
    pack_yt<<<dim3(N_ / 32, 8, T_), 256, 0, stream>>>(xw, feat, yt);
    pfy_gemm<<<dim3(N_ / 128, T_), 512, 0, stream>>>(P, yt, Z);
    hp_gemm<<<dim3(T_ * N_ / 64), 256, 0, stream>>>(feat, Z, W_hpf, b_hpf, b_lpf, xhi, xlo);

    // Z region dead from here — pack weights into it
    pack_w1c<<<dim3(8, 16), 256, 0, stream>>>(W1, w1chi, w1clo);
    pack_wc<<<dim3(1024 * 512 / 1024), 256, 0, stream>>>(W_ih, W_hh, wchi, wclo);
    pack_bias<<<dim3(4), 256, 0, stream>>>(b_ih, b_hh, bsum);

    // zero c (fp32, 4 MB) + h pair 0 (bf16 hi/lo, 4 MB): contiguous 8 MB
    hipMemsetAsync(ytreg, 0, (size_t)N_ * 256 * 4 + (size_t)N_ * 256 * 2 * 2, stream);

    for (int t = 0; t < T_; t++) {
        const short* hr_hi = (t & 1) ? hhi1 : hhi0;
        const short* hr_lo = (t & 1) ? hlo1 : hlo0;
        short* hw_hi = (t & 1) ? hhi0 : hhi1;
        short* hw_lo = (t & 1) ? hlo0 : hlo1;
        lstm_step<<<dim3(N_ / 128, 1024 / 128), 512, 0, stream>>>(
            xhi + (size_t)t * N_ * 256, xlo + (size_t)t * N_ * 256,
            hr_hi, hr_lo, wchi, wclo, bsum, cbuf, hw_hi, hw_lo);
    }
    // t=7 (odd) wrote pair 0 -> final h is hhi0/hlo0

    uv_gemm<<<dim3(N_ / 128, 512 / 128), 512, 0, stream>>>(hhi0, hlo0, w1chi, w1clo, UV);
    mlp_edge<<<dim3(E_ / 4), 256, 0, stream>>>(UV, eidx, b1, W2, b2, out);
}

// Round 16
// 407.525 us; speedup vs baseline: 1.0696x; 1.0696x over previous
//
#include <hip/hip_runtime.h>
#include <stdint.h>

#define T_ 8
#define N_ 4096
#define E_ 131072

typedef __attribute__((ext_vector_type(4))) float f32x4;
typedef __attribute__((ext_vector_type(8))) short s16x8;
typedef __attribute__((ext_vector_type(4))) short s16x4;

static __device__ __forceinline__ short f2bf(float f) {
    union { float f; unsigned u; } v; v.f = f;
    unsigned r = v.u + 0x7fffu + ((v.u >> 16) & 1u);   // RNE
    return (short)(r >> 16);
}
static __device__ __forceinline__ float bf2f(short s) {
    union { float f; unsigned u; } v; v.u = ((unsigned)(unsigned short)s) << 16;
    return v.f;
}

// barrier that does NOT drain vmcnt (validated round 14)
static __device__ __forceinline__ void bar_nodrain() {
    asm volatile("s_waitcnt lgkmcnt(0)\n\ts_barrier" ::: "memory");
}

// ---------------- Yt[t][j][n] (bf16) = X[t][n][j] transposed, j in [0,128) ----------------
__global__ __launch_bounds__(256) void pack_yt(const float* __restrict__ feat,
                                               short* __restrict__ yt) {
    __shared__ float tile[32][33];
    const int t = blockIdx.z, j0 = blockIdx.y * 32, n0 = blockIdx.x * 32;
    const float* src = feat + (size_t)t * N_ * 128 + j0;
    const int jj = threadIdx.x & 31, i4 = threadIdx.x >> 5;
#pragma unroll
    for (int s = 0; s < 4; s++) {
        int ii = i4 * 4 + s;
        tile[ii][jj] = src[(size_t)(n0 + ii) * 128 + jj];
    }
    __syncthreads();
    const int nn = threadIdx.x & 31, j4 = threadIdx.x >> 5;
#pragma unroll
    for (int s = 0; s < 4; s++) {
        int j2 = j4 * 4 + s;
        yt[(size_t)(t * 128 + j0 + j2) * N_ + n0 + nn] = f2bf(tile[nn][j2]);
    }
}

// ---------------- PX[t] = P[t] @ X[t]   (bf16 MFMA, fp32 acc; N=128) ----------------
// Re-association: low = relu((P@X)@Wlp + b) == relu(P@(X@Wlp) + b) up to fp32 rounding.
// Halved B/N vs round 14; same validated bar_nodrain pipeline (2 reg sets, dbuf LDS).
__global__ __launch_bounds__(512) void pfy_gemm(const float* __restrict__ P,
                                                const short* __restrict__ Yt,
                                                float* __restrict__ Z) {
    __shared__ short As[2][128][72];   // [buf][row][k], 144B stride
    __shared__ short Bs[2][128][72];   // [buf][col][k]
    const int t = blockIdx.y;
    const int m0 = blockIdx.x * 128;
    const int tid = threadIdx.x;
    const int lane = tid & 63, wid = tid >> 6;
    const int wm = wid >> 2, wn = wid & 3;       // wave grid 2(M) x 4(N)
    const int frow = lane & 15, kq = lane >> 4;  // MFMA fragment coords

    const float* Pt = P + (size_t)t * N_ * N_;
    const short* Bt = Yt + (size_t)t * 128 * N_;

    const int ar = tid >> 2;           // A row 0..127
    const int ak16 = (tid & 3) * 16;   // k offset (floats)
    const int bj = tid >> 2;           // B row 0..127
    const int bk16 = (tid & 3) * 16;   // k offset (shorts), 16 per thread

    f32x4 acc[4][2];
    f32x4 zf = {0.f, 0.f, 0.f, 0.f};
#pragma unroll
    for (int m = 0; m < 4; m++)
#pragma unroll
        for (int n = 0; n < 2; n++) acc[m][n] = zf;

    // two named register sets: even tiles -> set A, odd tiles -> set B
    f32x4 aA[4], aB[4]; s16x8 bA[2], bB[2];

    const float* Pr = &Pt[(size_t)(m0 + ar) * 4096 + ak16];
    const short* Br = &Bt[(size_t)bj * 4096 + bk16];

#define LOADA(KT) do { const int k0_ = (KT) * 64;                              \
        _Pragma("unroll") for (int i = 0; i < 4; i++)                          \
            aA[i] = *(const f32x4*)&Pr[k0_ + i * 4];                           \
        _Pragma("unroll") for (int i = 0; i < 2; i++)                          \
            bA[i] = *(const s16x8*)&Br[k0_ + i * 8]; } while (0)
#define LOADB(KT) do { const int k0_ = (KT) * 64;                              \
        _Pragma("unroll") for (int i = 0; i < 4; i++)                          \
            aB[i] = *(const f32x4*)&Pr[k0_ + i * 4];                           \
        _Pragma("unroll") for (int i = 0; i < 2; i++)                          \
            bB[i] = *(const s16x8*)&Br[k0_ + i * 8]; } while (0)
#define STOREA(BUF) do {                                                       \
        _Pragma("unroll") for (int i = 0; i < 4; i++) {                        \
            s16x4 c4_;                                                         \
            _Pragma("unroll") for (int j = 0; j < 4; j++) c4_[j] = f2bf(aA[i][j]); \
            *(s16x4*)&As[BUF][ar][ak16 + i * 4] = c4_; }                       \
        _Pragma("unroll") for (int i = 0; i < 2; i++)                          \
            *(s16x8*)&Bs[BUF][bj][bk16 + i * 8] = bA[i]; } while (0)
#define STOREB(BUF) do {                                                       \
        _Pragma("unroll") for (int i = 0; i < 4; i++) {                        \
            s16x4 c4_;                                                         \
            _Pragma("unroll") for (int j = 0; j < 4; j++) c4_[j] = f2bf(aB[i][j]); \
            *(s16x4*)&As[BUF][ar][ak16 + i * 4] = c4_; }                       \
        _Pragma("unroll") for (int i = 0; i < 2; i++)                          \
            *(s16x8*)&Bs[BUF][bj][bk16 + i * 8] = bB[i]; } while (0)

    auto compute_t = [&](int buf) {
#pragma unroll
        for (int ks = 0; ks < 2; ks++) {
            s16x8 af[4], bfr[2];
#pragma unroll
            for (int m = 0; m < 4; m++)
                af[m] = *(const s16x8*)&As[buf][wm * 64 + m * 16 + frow][kq * 8 + ks * 32];
#pragma unroll
            for (int n = 0; n < 2; n++)
                bfr[n] = *(const s16x8*)&Bs[buf][wn * 32 + n * 16 + frow][kq * 8 + ks * 32];
#pragma unroll
            for (int m = 0; m < 4; m++)
#pragma unroll
                for (int n = 0; n < 2; n++)
                    acc[m][n] = __builtin_amdgcn_mfma_f32_16x16x32_bf16(af[m], bfr[n], acc[m][n], 0, 0, 0);
        }
    };

    // prologue: tile0 -> buf0; tiles 1,2 in flight across the barrier
    LOADA(0);
    STOREA(0);
    LOADB(1);
    LOADA(2);
    bar_nodrain();

#pragma unroll 2
    for (int kt = 0; kt < 64; kt++) {
        compute_t(kt & 1);
        if (kt < 63) {
            if ((kt & 1) == 0) {
                STOREB(1);
                if (kt + 3 < 64) LOADB(kt + 3);
            } else {
                STOREA(0);
                if (kt + 3 < 64) LOADA(kt + 3);
            }
            bar_nodrain();
        }
    }
#undef LOADA
#undef LOADB
#undef STOREA
#undef STOREB

    float* Zt = Z + (size_t)t * N_ * 128;
#pragma unroll
    for (int m = 0; m < 4; m++)
#pragma unroll
        for (int n = 0; n < 2; n++)
#pragma unroll
            for (int r = 0; r < 4; r++) {
                int row = m0 + wm * 64 + m * 16 + kq * 4 + r;  // C/D: row=(lane>>4)*4+reg
                int col = wn * 32 + n * 16 + frow;             //      col=lane&15
                Zt[(size_t)row * 128 + col] = acc[m][n][r];
            }
}

// ---------------- filter heads: mode 0: low = relu(PX@Wlp + b_lpf) -> xseq[:, :128]
//                  mode 1: high = relu((X-PX)@Whp + b_hpf) -> xseq[:, 128:]
// Both bf16 hi/lo outputs. Structure = proven hp_gemm.
__global__ __launch_bounds__(256) void hp2_gemm(const float* __restrict__ feat,
                                                const float* __restrict__ PX,
                                                const float* __restrict__ Wlp,
                                                const float* __restrict__ Whp,
                                                const float* __restrict__ b_lpf,
                                                const float* __restrict__ b_hpf,
                                                short* __restrict__ xhi,
                                                short* __restrict__ xlo) {
    __shared__ float As[32][68];
    __shared__ float Ws[32][132];
    const int m0 = blockIdx.x * 64;
    const int mode = blockIdx.y;            // 0 = low, 1 = high
    const float* W = mode ? Whp : Wlp;
    const float* bp = mode ? b_hpf : b_lpf;
    const int tid = threadIdx.x;
    const int rg = tid & 15, cg = tid >> 4;
    float acc[4][8];
#pragma unroll
    for (int r = 0; r < 4; r++)
#pragma unroll
        for (int c = 0; c < 8; c++) acc[r][c] = 0.f;

    for (int k0 = 0; k0 < 128; k0 += 32) {
#pragma unroll
        for (int s = 0; s < 2; s++) {
            int q = tid + s * 256, row = q >> 3, k4 = q & 7;
            f32x4 pv = *(const f32x4*)&PX[(size_t)(m0 + row) * 128 + k0 + k4 * 4];
            f32x4 v;
            if (mode) {
                f32x4 fv = *(const f32x4*)&feat[(size_t)(m0 + row) * 128 + k0 + k4 * 4];
#pragma unroll
                for (int i = 0; i < 4; i++) v[i] = fv[i] - pv[i];
            } else {
                v = pv;
            }
#pragma unroll
            for (int i = 0; i < 4; i++) As[k4 * 4 + i][row] = v[i];
        }
#pragma unroll
        for (int s = 0; s < 4; s++) {
            int q = tid + s * 256, kk = q >> 5, j4 = q & 31;
            *(f32x4*)&Ws[kk][j4 * 4] = *(const f32x4*)&W[(size_t)(k0 + kk) * 128 + j4 * 4];
        }
        __syncthreads();
#pragma unroll
        for (int kk = 0; kk < 32; kk++) {
            f32x4 a  = *(const f32x4*)&As[kk][rg * 4];
            f32x4 w0 = *(const f32x4*)&Ws[kk][cg * 8];
            f32x4 w1 = *(const f32x4*)&Ws[kk][cg * 8 + 4];
#pragma unroll
            for (int r = 0; r < 4; r++)
#pragma unroll
                for (int c = 0; c < 4; c++) {
                    acc[r][c]     += a[r] * w0[c];
                    acc[r][c + 4] += a[r] * w1[c];
                }
        }
        __syncthreads();
    }
    float bh[8];
#pragma unroll
    for (int c = 0; c < 8; c++) bh[c] = bp[cg * 8 + c];
#pragma unroll
    for (int r = 0; r < 4; r++) {
        s16x4 h0, h1, l0, l1;
#pragma unroll
        for (int c = 0; c < 4; c++) {
            float v0 = fmaxf(acc[r][c] + bh[c], 0.f);
            float v1 = fmaxf(acc[r][c + 4] + bh[c + 4], 0.f);
            h0[c] = f2bf(v0); l0[c] = f2bf(v0 - bf2f(h0[c]));
            h1[c] = f2bf(v1); l1[c] = f2bf(v1 - bf2f(h1[c]));
        }
        size_t base = (size_t)(m0 + rg * 4 + r) * 256 + mode * 128 + cg * 8;
        *(s16x4*)&xhi[base] = h0;  *(s16x4*)&xhi[base + 4] = h1;
        *(s16x4*)&xlo[base] = l0;  *(s16x4*)&xlo[base + 4] = l1;
    }
}

// ---------------- Wc gate-interleaved: packed row j <-> orig row (j&3)*256 + (j>>2) ----------------
__global__ __launch_bounds__(256) void pack_wc(const float* __restrict__ W_ih,
                                               const float* __restrict__ W_hh,
                                               short* __restrict__ whi,
                                               short* __restrict__ wlo) {
    int idx = (blockIdx.x * 256 + threadIdx.x) * 4;   // over 1024*512
    int j = idx >> 9, k = idx & 511;
    int orig = (j & 3) * 256 + (j >> 2);
    const float* src = (k < 256) ? &W_ih[(size_t)orig * 256 + k]
                                 : &W_hh[(size_t)orig * 256 + (k - 256)];
    f32x4 v = *(const f32x4*)src;
    s16x4 hi, lo;
#pragma unroll
    for (int i = 0; i < 4; i++) {
        hi[i] = f2bf(v[i]);
        lo[i] = f2bf(v[i] - bf2f(hi[i]));
    }
    *(s16x4*)&whi[idx] = hi;
    *(s16x4*)&wlo[idx] = lo;
}

// ---------------- bsum[j] = b_ih[orig(j)] + b_hh[orig(j)], gate-interleaved ----------------
__global__ void pack_bias(const float* __restrict__ b_ih,
                          const float* __restrict__ b_hh,
                          float* __restrict__ bsum) {
    int j = blockIdx.x * 256 + threadIdx.x;
    int orig = (j & 3) * 256 + (j >> 2);
    bsum[j] = b_ih[orig] + b_hh[orig];
}

// ---------------- fused LSTM step: gates GEMM + pointwise c/h ----------------
__global__ __launch_bounds__(512) void lstm_step(const short* __restrict__ xhi,
                                                 const short* __restrict__ xlo,
                                                 const short* __restrict__ hhi_r,
                                                 const short* __restrict__ hlo_r,
                                                 const short* __restrict__ wchi,
                                                 const short* __restrict__ wclo,
                                                 const float* __restrict__ bsum,
                                                 float* __restrict__ cbuf,
                                                 short* __restrict__ hhi_w,
                                                 short* __restrict__ hlo_w) {
    __shared__ short Ah[2][128][40], Al[2][128][40];
    __shared__ short Bh[2][128][40], Bl[2][128][40];
    __shared__ float gl[128][132];     // 16B-aligned row stride (528 B)
    const int m0 = blockIdx.x * 128;
    const int j0 = blockIdx.y * 128;
    const int tid = threadIdx.x;
    const int lane = tid & 63, wid = tid >> 6;
    const int wm = wid >> 2, wn = wid & 3;
    const int frow = lane & 15, kq = lane >> 4;

    const int sr = tid >> 2;
    const int sk8 = (tid & 3) * 8;

    f32x4 acc[4][2];
    f32x4 zf = {0.f, 0.f, 0.f, 0.f};
#pragma unroll
    for (int m = 0; m < 4; m++)
#pragma unroll
        for (int n = 0; n < 2; n++) acc[m][n] = zf;

    s16x8 a_h, a_l, b_h, b_l;

    auto load_t = [&](int kt) {
        const int k0 = kt * 32;
        const short* ah = (k0 < 256) ? xhi : hhi_r;
        const short* al = (k0 < 256) ? xlo : hlo_r;
        const size_t abase = (size_t)(m0 + sr) * 256 + (k0 & 255) + sk8;
        a_h = *(const s16x8*)&ah[abase];
        a_l = *(const s16x8*)&al[abase];
        const size_t bb = (size_t)(j0 + sr) * 512 + k0 + sk8;
        b_h = *(const s16x8*)&wchi[bb];
        b_l = *(const s16x8*)&wclo[bb];
    };
    auto store_t = [&](int buf) {
        *(s16x8*)&Ah[buf][sr][sk8] = a_h;
        *(s16x8*)&Al[buf][sr][sk8] = a_l;
        *(s16x8*)&Bh[buf][sr][sk8] = b_h;
        *(s16x8*)&Bl[buf][sr][sk8] = b_l;
    };
    auto compute_t = [&](int buf) {
        s16x8 afh[4], afl[4], bfh[2], bfl[2];
#pragma unroll
        for (int m = 0; m < 4; m++) {
            afh[m] = *(const s16x8*)&Ah[buf][wm * 64 + m * 16 + frow][kq * 8];
            afl[m] = *(const s16x8*)&Al[buf][wm * 64 + m * 16 + frow][kq * 8];
        }
#pragma unroll
        for (int n = 0; n < 2; n++) {
            bfh[n] = *(const s16x8*)&Bh[buf][wn * 32 + n * 16 + frow][kq * 8];
            bfl[n] = *(const s16x8*)&Bl[buf][wn * 32 + n * 16 + frow][kq * 8];
        }
#pragma unroll
        for (int m = 0; m < 4; m++)
#pragma unroll
            for (int n = 0; n < 2; n++) {
                acc[m][n] = __builtin_amdgcn_mfma_f32_16x16x32_bf16(afh[m], bfh[n], acc[m][n], 0, 0, 0);
                acc[m][n] = __builtin_amdgcn_mfma_f32_16x16x32_bf16(afh[m], bfl[n], acc[m][n], 0, 0, 0);
                acc[m][n] = __builtin_amdgcn_mfma_f32_16x16x32_bf16(afl[m], bfh[n], acc[m][n], 0, 0, 0);
            }
    };

    load_t(0);
    store_t(0);
    bar_nodrain();
#pragma unroll 2
    for (int kt = 0; kt < 16; kt++) {
        const int cur = kt & 1;
        if (kt < 15) load_t(kt + 1);
        compute_t(cur);
        bar_nodrain();
        if (kt < 15) { store_t(cur ^ 1); bar_nodrain(); }
    }

    // epilogue: acc -> gl tile (distinct LDS array)
#pragma unroll
    for (int m = 0; m < 4; m++)
#pragma unroll
        for (int n = 0; n < 2; n++)
#pragma unroll
            for (int r = 0; r < 4; r++)
                gl[wm * 64 + m * 16 + kq * 4 + r][wn * 32 + n * 16 + frow] = acc[m][n][r];
    bar_nodrain();

    // pointwise: thread -> (row, 8 channels); gates i,f,g,o adjacent in packed cols
    const int erow = tid >> 2;
    const int ec0 = (tid & 3) * 8;
    const size_t cbase = (size_t)(m0 + erow) * 256 + blockIdx.y * 32 + ec0;
    f32x4 co0 = *(const f32x4*)&cbuf[cbase];
    f32x4 co1 = *(const f32x4*)&cbuf[cbase + 4];
    f32x4 cn0, cn1;
    s16x8 h8, l8;
#pragma unroll
    for (int i = 0; i < 8; i++) {
        f32x4 g4 = *(const f32x4*)&gl[erow][(ec0 + i) * 4];
        f32x4 bs = *(const f32x4*)&bsum[j0 + (ec0 + i) * 4];
        float si = 1.f / (1.f + expf(-(g4[0] + bs[0])));
        float sf = 1.f / (1.f + expf(-(g4[1] + bs[1])));
        float tg = tanhf(g4[2] + bs[2]);
        float so = 1.f / (1.f + expf(-(g4[3] + bs[3])));
        float cold = (i < 4) ? co0[i] : co1[i - 4];
        float cn = sf * cold + si * tg;
        float hv = so * tanhf(cn);
        if (i < 4) cn0[i] = cn; else cn1[i - 4] = cn;
        h8[i] = f2bf(hv);
        l8[i] = f2bf(hv - bf2f(h8[i]));
    }
    *(f32x4*)&cbuf[cbase] = cn0;
    *(f32x4*)&cbuf[cbase + 4] = cn1;
    *(s16x8*)&hhi_w[cbase] = h8;
    *(s16x8*)&hlo_w[cbase] = l8;
}

// ---------------- W1 [512][256] -> combined per-node weight Bc[j][k] hi/lo ----------------
__global__ __launch_bounds__(256) void pack_w1c(const float* __restrict__ W1,
                                                short* __restrict__ whi,
                                                short* __restrict__ wlo) {
    __shared__ float tile[32][33];
    const int k0 = blockIdx.x * 32;
    const int j0 = blockIdx.y * 32;
    const int koff = (j0 >= 256) ? 256 : 0;
    const int joff = (j0 >= 256) ? 256 : 0;
    const int jj = threadIdx.x & 31, k4 = threadIdx.x >> 5;
#pragma unroll
    for (int s = 0; s < 4; s++) {
        int kk = k4 * 4 + s;
        tile[kk][jj] = W1[(size_t)(k0 + kk + koff) * 256 + (j0 + jj - joff)];
    }
    __syncthreads();
    const int kk2 = threadIdx.x & 31, j4 = threadIdx.x >> 5;
#pragma unroll
    for (int s = 0; s < 4; s++) {
        int j2 = j4 * 4 + s;
        float v = tile[kk2][j2];
        short hb = f2bf(v);
        whi[(size_t)(j0 + j2) * 256 + k0 + kk2] = hb;
        wlo[(size_t)(j0 + j2) * 256 + k0 + kk2] = f2bf(v - bf2f(hb));
    }
}

// ---------------- UV = h @ Bc^T  (M=4096, K=256, N=512) ----------------
__global__ __launch_bounds__(512) void uv_gemm(const short* __restrict__ hhi,
                                               const short* __restrict__ hlo,
                                               const short* __restrict__ whi,
                                               const short* __restrict__ wlo,
                                               float* __restrict__ UV) {
    __shared__ short Ah[2][128][40], Al[2][128][40];
    __shared__ short Bh[2][128][40], Bl[2][128][40];
    const int m0 = blockIdx.x * 128;
    const int j0 = blockIdx.y * 128;
    const int tid = threadIdx.x;
    const int lane = tid & 63, wid = tid >> 6;
    const int wm = wid >> 2, wn = wid & 3;
    const int frow = lane & 15, kq = lane >> 4;
    const int sr = tid >> 2;
    const int sk8 = (tid & 3) * 8;

    f32x4 acc[4][2];
    f32x4 zf = {0.f, 0.f, 0.f, 0.f};
#pragma unroll
    for (int m = 0; m < 4; m++)
#pragma unroll
        for (int n = 0; n < 2; n++) acc[m][n] = zf;

    s16x8 a_h, a_l, b_h, b_l;

    auto load_t = [&](int kt) {
        const int k0 = kt * 32;
        const size_t abase = (size_t)(m0 + sr) * 256 + k0 + sk8;
        a_h = *(const s16x8*)&hhi[abase];
        a_l = *(const s16x8*)&hlo[abase];
        const size_t bb = (size_t)(j0 + sr) * 256 + k0 + sk8;
        b_h = *(const s16x8*)&whi[bb];
        b_l = *(const s16x8*)&wlo[bb];
    };
    auto store_t = [&](int buf) {
        *(s16x8*)&Ah[buf][sr][sk8] = a_h;
        *(s16x8*)&Al[buf][sr][sk8] = a_l;
        *(s16x8*)&Bh[buf][sr][sk8] = b_h;
        *(s16x8*)&Bl[buf][sr][sk8] = b_l;
    };
    auto compute_t = [&](int buf) {
        s16x8 afh[4], afl[4], bfh[2], bfl[2];
#pragma unroll
        for (int m = 0; m < 4; m++) {
            afh[m] = *(const s16x8*)&Ah[buf][wm * 64 + m * 16 + frow][kq * 8];
            afl[m] = *(const s16x8*)&Al[buf][wm * 64 + m * 16 + frow][kq * 8];
        }
#pragma unroll
        for (int n = 0; n < 2; n++) {
            bfh[n] = *(const s16x8*)&Bh[buf][wn * 32 + n * 16 + frow][kq * 8];
            bfl[n] = *(const s16x8*)&Bl[buf][wn * 32 + n * 16 + frow][kq * 8];
        }
#pragma unroll
        for (int m = 0; m < 4; m++)
#pragma unroll
            for (int n = 0; n < 2; n++) {
                acc[m][n] = __builtin_amdgcn_mfma_f32_16x16x32_bf16(afh[m], bfh[n], acc[m][n], 0, 0, 0);
                acc[m][n] = __builtin_amdgcn_mfma_f32_16x16x32_bf16(afh[m], bfl[n], acc[m][n], 0, 0, 0);
                acc[m][n] = __builtin_amdgcn_mfma_f32_16x16x32_bf16(afl[m], bfh[n], acc[m][n], 0, 0, 0);
            }
    };

    load_t(0);
    store_t(0);
    bar_nodrain();
#pragma unroll 2
    for (int kt = 0; kt < 8; kt++) {
        const int cur = kt & 1;
        if (kt < 7) load_t(kt + 1);
        compute_t(cur);
        bar_nodrain();
        if (kt < 7) { store_t(cur ^ 1); bar_nodrain(); }
    }

#pragma unroll
    for (int m = 0; m < 4; m++)
#pragma unroll
        for (int n = 0; n < 2; n++)
#pragma unroll
            for (int r = 0; r < 4; r++) {
                int row = m0 + wm * 64 + m * 16 + kq * 4 + r;
                int col = j0 + wn * 32 + n * 16 + frow;
                UV[(size_t)row * 512 + col] = acc[m][n][r];
            }
}

// ---------------- per-edge: logit = relu(U[src]+V[dst]+b1) . W2 + b2 ----------------
__global__ __launch_bounds__(256) void mlp_edge(const float* __restrict__ UV,
                                                const int* __restrict__ eidx,
                                                const float* __restrict__ b1,
                                                const float* __restrict__ W2,
                                                const float* __restrict__ b2,
                                                float* __restrict__ out) {
    const int e = blockIdx.x * 4 + (threadIdx.x >> 6);
    const int lane = threadIdx.x & 63;
    const int c4 = lane * 4;
    const int src = eidx[e];
    const int dst = eidx[E_ + e];
    f32x4 u = *(const f32x4*)&UV[(size_t)src * 512 + c4];
    f32x4 v = *(const f32x4*)&UV[(size_t)dst * 512 + 256 + c4];
    f32x4 bb = *(const f32x4*)&b1[c4];
    f32x4 ww = *(const f32x4*)&W2[c4];
    float p = 0.f;
#pragma unroll
    for (int i = 0; i < 4; i++)
        p += fmaxf(u[i] + v[i] + bb[i], 0.f) * ww[i];
    p += __shfl_xor(p, 1);
    p += __shfl_xor(p, 2);
    p += __shfl_xor(p, 4);
    p += __shfl_xor(p, 8);
    p += __shfl_xor(p, 16);
    p += __shfl_xor(p, 32);
    if (lane == 0) out[e] = p + b2[0];
}

extern "C" void kernel_launch(void* const* d_in, const int* in_sizes, int n_in,
                              void* d_out, int out_size, void* d_ws, size_t ws_size,
                              hipStream_t stream) {
    (void)in_sizes; (void)n_in; (void)out_size; (void)ws_size;
    const float* feat  = (const float*)d_in[0];
    const float* P     = (const float*)d_in[1];
    const int*   eidx  = (const int*)d_in[2];
    const float* W_lpf = (const float*)d_in[3];
    const float* b_lpf = (const float*)d_in[4];
    const float* W_hpf = (const float*)d_in[5];
    const float* b_hpf = (const float*)d_in[6];
    const float* W_ih  = (const float*)d_in[7];
    const float* W_hh  = (const float*)d_in[8];
    const float* b_ih  = (const float*)d_in[9];
    const float* b_hh  = (const float*)d_in[10];
    const float* W1    = (const float*)d_in[11];
    const float* b1    = (const float*)d_in[12];
    const float* W2    = (const float*)d_in[13];
    const float* b2    = (const float*)d_in[14];
    float* out = (float*)d_out;

    // workspace layout (100.7 MB)
    char* ws = (char*)d_ws;
    float* xw    = (float*)ws;   ws += (size_t)T_ * N_ * 128 * 4;   // 16.78 MB (unused scratch)
    char*  ytreg = ws;           ws += (size_t)T_ * 256 * N_ * 2;   // 16.78 MB; yt then c + h dbuf
    char*  Zreg  = ws;           ws += (size_t)T_ * N_ * 256 * 4;   // 33.55 MB; PX then packs+UV
    short* xhi   = (short*)ws;   ws += (size_t)T_ * N_ * 256 * 2;   // 16.78 MB
    short* xlo   = (short*)ws;   ws += (size_t)T_ * N_ * 256 * 2;   // 16.78 MB
    (void)xw;

    short* yt    = (short*)ytreg;                 // 8.4 MB (T*128*N bf16)
    float* PX    = (float*)Zreg;                  // 16.8 MB (T*N*128 fp32)
    // ytreg after pfy: c (4 MB) + double-buffered h hi/lo (4 x 2 MB)
    float* cbuf  = (float*)ytreg;
    short* hhi0  = (short*)(ytreg + (size_t)N_ * 256 * 4);
    short* hlo0  = hhi0 + (size_t)N_ * 256;
    short* hhi1  = hlo0 + (size_t)N_ * 256;
    short* hlo1  = hhi1 + (size_t)N_ * 256;
    // Zreg after hp2_gemm: W packs + bias + UV (PX dead)
    short* w1chi = (short*)Zreg;
    short* w1clo = w1chi + (size_t)512 * 256;
    short* wchi  = w1clo + (size_t)512 * 256;
    short* wclo  = wchi + (size_t)1024 * 512;
    float* bsum  = (float*)(wclo + (size_t)1024 * 512);
    float* UV    = bsum + 1024;

    pack_yt<<<dim3(N_ / 32, 4, T_), 256, 0, stream>>>(feat, yt);
    pfy_gemm<<<dim3(N_ / 128, T_), 512, 0, stream>>>(P, yt, PX);
    hp2_gemm<<<dim3(T_ * N_ / 64, 2), 256, 0, stream>>>(feat, PX, W_lpf, W_hpf,
                                                        b_lpf, b_hpf, xhi, xlo);

    // PX dead from here — pack weights into Zreg
    pack_w1c<<<dim3(8, 16), 256, 0, stream>>>(W1, w1chi, w1clo);
    pack_wc<<<dim3(1024 * 512 / 1024), 256, 0, stream>>>(W_ih, W_hh, wchi, wclo);
    pack_bias<<<dim3(4), 256, 0, stream>>>(b_ih, b_hh, bsum);

    // zero c (fp32, 4 MB) + h pair 0 (bf16 hi/lo, 4 MB): contiguous 8 MB
    hipMemsetAsync(ytreg, 0, (size_t)N_ * 256 * 4 + (size_t)N_ * 256 * 2 * 2, stream);

    for (int t = 0; t < T_; t++) {
        const short* hr_hi = (t & 1) ? hhi1 : hhi0;
        const short* hr_lo = (t & 1) ? hlo1 : hlo0;
        short* hw_hi = (t & 1) ? hhi0 : hhi1;
        short* hw_lo = (t & 1) ? hlo0 : hlo1;
        lstm_step<<<dim3(N_ / 128, 1024 / 128), 512, 0, stream>>>(
            xhi + (size_t)t * N_ * 256, xlo + (size_t)t * N_ * 256,
            hr_hi, hr_lo, wchi, wclo, bsum, cbuf, hw_hi, hw_lo);
    }
    // t=7 (odd) wrote pair 0 -> final h is hhi0/hlo0

    uv_gemm<<<dim3(N_ / 128, 512 / 128), 512, 0, stream>>>(hhi0, hlo0, w1chi, w1clo, UV);
    mlp_edge<<<dim3(E_ / 4), 256, 0, stream>>>(UV, eidx, b1, W2, b2, out);
}